// Round 7
// baseline (1361.904 us; speedup 1.0000x reference)
//
#include <hip/hip_runtime.h>
#include <stdint.h>

// VQ-VAE vector quantizer — fp32, NCHW input [64,64,32,32], emb [1024,64].
// Two-phase exact argmin:
//   pass0/pass1: bf16 MFMA scores S=X·E^T with rigorous error window
//     |S - G| <= 2^-7 * sqrt(A) * emax  (Cauchy-Schwarz over bf16 rounding)
//   candidates: d~ <= d~min + W, W = 2*(2^-6*sqrt(A)*emax + 6e-5) — provable
//     superset of all k whose EXACT fp32 ref distance can equal the ref min.
//   final: bit-exact np fp32 expression (r3-proven: absmax 0.0) evaluated
//     only on candidates (~1.4/point), first-index tie-break; r6 epilogue.
constexpr int KCODES = 1024;
constexpr int DDIM   = 64;
constexpr int HW     = 1024;
constexpr int NPTS   = 65536;

constexpr int OUT_Q    = 0;
constexpr int OUT_IDX  = 4194304;
constexpr int OUT_LOSS = 4259840;
constexpr int OUT_NLL  = 4259841;

// ws float-offsets (total ~11.4 MB)
constexpr size_t WS_C      = 0;                      // 1024 f  : C_k=||e_k||^2 (np-pairwise)
constexpr size_t WS_LOSS   = 1024;
constexpr size_t WS_TICKET = 1025;
constexpr size_t WS_EMAX   = 1026;
constexpr size_t WS_A      = 2048;                   // 65536 f : A_n=||x_n||^2 (np-pairwise)
constexpr size_t WS_DMIN   = WS_A + NPTS;            // 65536 f : per-point approx min dist
constexpr size_t WS_CNT    = WS_DMIN + NPTS;         // 65536 int
constexpr size_t WS_CAND   = WS_CNT + NPTS;          // 65536*16 u16 = 524288 f
constexpr size_t WS_EB     = WS_CAND + (size_t)NPTS * 8;   // 1024*64 bf16 = 32768 f
constexpr size_t WS_XB     = WS_EB + 16384;          // 65536*64 bf16 = 2097152 f

typedef __attribute__((ext_vector_type(8))) short short8v;
typedef __attribute__((ext_vector_type(4))) float float4v;

__device__ __forceinline__ uint16_t f2bf(float f) {   // RNE fp32->bf16
    uint32_t u = __float_as_uint(f);
    return (uint16_t)((u + 0x7fffu + ((u >> 16) & 1u)) >> 16);
}

// numpy pairwise sum-of-squares for n=64 (verified bit-exact in r3-r6)
__device__ __forceinline__ float np_pairwise_sumsq64(const float* a) {
    float r[8];
    #pragma unroll
    for (int j = 0; j < 8; ++j) r[j] = __fmul_rn(a[j], a[j]);
    #pragma unroll
    for (int i = 8; i < 64; i += 8)
        #pragma unroll
        for (int j = 0; j < 8; ++j)
            r[j] = __fadd_rn(r[j], __fmul_rn(a[i + j], a[i + j]));
    return __fadd_rn(__fadd_rn(__fadd_rn(r[0], r[1]), __fadd_rn(r[2], r[3])),
                     __fadd_rn(__fadd_rn(r[4], r[5]), __fadd_rn(r[6], r[7])));
}

// ---- prep: X -> bf16 rows + exact A_n + cnt=0 -------------------------------
__global__ __launch_bounds__(256) void vq_prep_x(const float* __restrict__ inp,
                                                 float* __restrict__ ws) {
    const int tid = threadIdx.x;
    const int n = blockIdx.x * 256 + tid;
    const int b = n >> 10, hw = n & 1023;
    const float* xin = inp + (size_t)b * DDIM * HW + hw;
    float x[DDIM];
    #pragma unroll
    for (int d = 0; d < DDIM; ++d) x[d] = xin[(size_t)d * HW];
    ws[WS_A + n] = np_pairwise_sumsq64(x);
    ((int*)ws)[WS_CNT + n] = 0;
    uint32_t* xb = (uint32_t*)(ws + WS_XB) + (size_t)n * 32;
    #pragma unroll
    for (int j = 0; j < 32; ++j)
        xb[j] = (uint32_t)f2bf(x[2 * j]) | ((uint32_t)f2bf(x[2 * j + 1]) << 16);
}

// ---- prep: E -> bf16 rows + exact C_k + emax + init scalars -----------------
__global__ __launch_bounds__(1024) void vq_prep_e(const float* __restrict__ emb,
                                                  float* __restrict__ ws) {
    __shared__ float smax[16];
    const int k = threadIdx.x;
    float row[DDIM];
    const float4* src = (const float4*)(emb + (size_t)k * DDIM);
    #pragma unroll
    for (int j = 0; j < 16; ++j) ((float4*)row)[j] = src[j];
    float C = np_pairwise_sumsq64(row);
    ws[WS_C + k] = C;
    uint32_t* ebr = (uint32_t*)(ws + WS_EB) + (size_t)k * 32;
    #pragma unroll
    for (int j = 0; j < 32; ++j)
        ebr[j] = (uint32_t)f2bf(row[2 * j]) | ((uint32_t)f2bf(row[2 * j + 1]) << 16);
    float m = C;
    #pragma unroll
    for (int off = 32; off > 0; off >>= 1) m = fmaxf(m, __shfl_down(m, off, 64));
    if ((k & 63) == 0) smax[k >> 6] = m;
    __syncthreads();
    if (k == 0) {
        float mm = smax[0];
        #pragma unroll
        for (int i = 1; i < 16; ++i) mm = fmaxf(mm, smax[i]);
        ws[WS_EMAX] = sqrtf(mm);                       // emax = max ||e_k||
        ws[WS_LOSS] = 0.0f;
        ((unsigned*)ws)[WS_TICKET] = 0u;
    }
}

// ---- GEMM passes: MODE 0 = per-point d~min; MODE 1 = emit candidates --------
// Block 256 thr = 4 waves; wave owns 32 points (2 MFMA row-groups), scans all
// 1024 codes in 16-code chunks. A-frag: lane holds X[m=lane&15][k=quad*8+j]
// (m120-verified A layout); B-frag identical addressing into E rows; C/D:
// col=lane&15 (code), row=quad*4+reg (point) (m89-verified).
template <int MODE>
__global__ __launch_bounds__(256) void vq_pass(float* __restrict__ ws) {
    const int tid  = threadIdx.x;
    const int lane = tid & 63;
    const int wave = tid >> 6;
    const int col  = lane & 15;
    const int quad = lane >> 4;
    const int base = blockIdx.x * 128 + wave * 32;

    const uint16_t* Xb = (const uint16_t*)(ws + WS_XB);
    const uint16_t* Eb = (const uint16_t*)(ws + WS_EB);
    const float* Cw = ws + WS_C;
    const float* Aw = ws + WS_A;

    short8v a[2][2];
    #pragma unroll
    for (int g = 0; g < 2; ++g) {
        const uint16_t* xr = Xb + (size_t)(base + g * 16 + col) * DDIM + quad * 8;
        a[g][0] = *(const short8v*)(xr);
        a[g][1] = *(const short8v*)(xr + 32);
    }
    float Ap[2][4];
    #pragma unroll
    for (int g = 0; g < 2; ++g)
        #pragma unroll
        for (int r = 0; r < 4; ++r)
            Ap[g][r] = Aw[base + g * 16 + quad * 4 + r];

    float run[2][4];
    float thr[2][4];
    if (MODE == 0) {
        #pragma unroll
        for (int g = 0; g < 2; ++g)
            #pragma unroll
            for (int r = 0; r < 4; ++r) run[g][r] = 3.0e38f;
    } else {
        const float emax = ws[WS_EMAX];
        const float* dmin = ws + WS_DMIN;
        #pragma unroll
        for (int g = 0; g < 2; ++g)
            #pragma unroll
            for (int r = 0; r < 4; ++r) {
                int p = base + g * 16 + quad * 4 + r;
                float W = 2.0f * (0.015625f * sqrtf(Ap[g][r]) * emax + 6e-5f);
                thr[g][r] = dmin[p] + W;
            }
    }
    int* cnt = (int*)ws + WS_CNT;
    uint16_t* cand = (uint16_t*)(ws + WS_CAND);

    #pragma unroll 1
    for (int c = 0; c < 64; ++c) {
        const int kc = c * 16 + col;
        const uint16_t* er = Eb + (size_t)kc * DDIM + quad * 8;
        short8v b0 = *(const short8v*)(er);
        short8v b1 = *(const short8v*)(er + 32);
        float Ck = Cw[kc];
        #pragma unroll
        for (int g = 0; g < 2; ++g) {
            float4v acc = {0.f, 0.f, 0.f, 0.f};
            acc = __builtin_amdgcn_mfma_f32_16x16x32_bf16(a[g][0], b0, acc, 0, 0, 0);
            acc = __builtin_amdgcn_mfma_f32_16x16x32_bf16(a[g][1], b1, acc, 0, 0, 0);
            #pragma unroll
            for (int r = 0; r < 4; ++r) {
                float dk = fmaf(-2.0f, acc[r], Ap[g][r]) + Ck;
                if (MODE == 0) {
                    run[g][r] = fminf(run[g][r], dk);
                } else {
                    if (dk <= thr[g][r]) {
                        int p = base + g * 16 + quad * 4 + r;
                        int slot = atomicAdd(&cnt[p], 1);
                        if (slot < 16) cand[(size_t)p * 16 + slot] = (uint16_t)kc;
                    }
                }
            }
        }
    }
    if (MODE == 0) {
        float* dmin = ws + WS_DMIN;
        #pragma unroll
        for (int g = 0; g < 2; ++g)
            #pragma unroll
            for (int r = 0; r < 4; ++r) {
                float m = run[g][r];
                m = fminf(m, __shfl_xor(m, 1, 16));
                m = fminf(m, __shfl_xor(m, 2, 16));
                m = fminf(m, __shfl_xor(m, 4, 16));
                m = fminf(m, __shfl_xor(m, 8, 16));
                if (col == 0) dmin[base + g * 16 + quad * 4 + r] = m;
            }
    }
}

// bit-exact ref distance: d = fp32( fp32(A - 2*G_seq) + C_k )
__device__ __forceinline__ float exact_dist(const float* x,
                                            const float* __restrict__ emb,
                                            const float* __restrict__ Cw,
                                            float A, int k) {
    float e[DDIM];
    const float4* e4 = (const float4*)(emb + (size_t)k * DDIM);
    #pragma unroll
    for (int j = 0; j < 16; ++j) ((float4*)e)[j] = e4[j];
    float g = 0.f;
    #pragma unroll
    for (int d = 0; d < DDIM; ++d) g = fmaf(x[d], e[d], g);
    return __fadd_rn(__fsub_rn(A, __fmul_rn(2.0f, g)), Cw[k]);
}

// ---- final: exact eval of candidates + full epilogue (r6-proven) ------------
__global__ __launch_bounds__(256) void vq_final(const float* __restrict__ inp,
        const float* __restrict__ emb, float* __restrict__ ws,
        float* __restrict__ out, int nblocks) {
    __shared__ float sred[4];
    const int tid  = threadIdx.x;
    const int lane = tid & 63;
    const int wave = tid >> 6;
    const int n  = blockIdx.x * 256 + tid;
    const int b  = n >> 10, hw = n & 1023;
    const float* xin = inp + (size_t)b * DDIM * HW + hw;
    float x[DDIM];
    #pragma unroll
    for (int d = 0; d < DDIM; ++d) x[d] = xin[(size_t)d * HW];
    #pragma unroll
    for (int d = 0; d < DDIM; ++d) __asm__ volatile("" : "+v"(x[d]));

    const float A = ws[WS_A + n];
    const float* Cw = ws + WS_C;
    const int cnt = ((const int*)ws)[WS_CNT + n];
    const uint16_t* cand = (const uint16_t*)(ws + WS_CAND) + (size_t)n * 16;

    int bi;
    if (cnt == 1) {
        bi = cand[0];                    // sole candidate IS the ref argmin
    } else if (cnt >= 2 && cnt <= 16) {
        float bd = 3.0e38f; bi = KCODES - 1;
        #pragma unroll 1
        for (int c = 0; c < cnt; ++c) {
            int k = cand[c];
            float dd = exact_dist(x, emb, Cw, A, k);
            if (dd < bd || (dd == bd && k < bi)) { bd = dd; bi = k; }
        }
    } else {                             // overflow / safety: full exact scan
        float bd = 3.0e38f; bi = 0;
        #pragma unroll 1
        for (int k = 0; k < KCODES; ++k) {
            float dd = exact_dist(x, emb, Cw, A, k);
            if (dd < bd) { bd = dd; bi = k; }
        }
    }
    out[OUT_IDX + n] = (float)bi;

    // epilogue: out = fp32(x + fp32(q - x)) written NCHW; loss partial
    float* orow = out + OUT_Q + (size_t)b * DDIM * HW + hw;
    const float4* q4 = (const float4*)(emb + (size_t)bi * DDIM);
    float lacc = 0.f;
    #pragma unroll
    for (int j = 0; j < 16; ++j) {
        float4 qv = q4[j];
        #pragma unroll
        for (int i = 0; i < 4; ++i) {
            const int d = j * 4 + i;
            float q = (i == 0) ? qv.x : (i == 1) ? qv.y : (i == 2) ? qv.z : qv.w;
            float diff = __fsub_rn(q, x[d]);
            orow[(size_t)d * HW] = __fadd_rn(x[d], diff);
            lacc = fmaf(diff, diff, lacc);
        }
    }
    #pragma unroll
    for (int off = 32; off > 0; off >>= 1) lacc += __shfl_down(lacc, off, 64);
    if (lane == 0) sred[wave] = lacc;
    __syncthreads();
    if (tid == 0) {
        atomicAdd(ws + WS_LOSS, sred[0] + sred[1] + sred[2] + sred[3]);
        __threadfence();
        unsigned old = atomicAdd((unsigned*)ws + WS_TICKET, 1u);
        if (old == (unsigned)(nblocks - 1)) {
            __threadfence();
            float L = __hip_atomic_load(ws + WS_LOSS, __ATOMIC_RELAXED,
                                        __HIP_MEMORY_SCOPE_AGENT);
            out[OUT_LOSS] = L * (1.25f / 4194304.0f);
            out[OUT_NLL]  = 1.0f;
        }
    }
}

extern "C" void kernel_launch(void* const* d_in, const int* in_sizes, int n_in,
                              void* d_out, int out_size, void* d_ws, size_t ws_size,
                              hipStream_t stream) {
    const float* inp = (const float*)d_in[0];
    const float* emb = (const float*)d_in[1];
    float* out = (float*)d_out;
    float* ws  = (float*)d_ws;

    vq_prep_x<<<NPTS / 256, 256, 0, stream>>>(inp, ws);
    vq_prep_e<<<1, 1024, 0, stream>>>(emb, ws);
    vq_pass<0><<<512, 256, 0, stream>>>(ws);
    vq_pass<1><<<512, 256, 0, stream>>>(ws);
    vq_final<<<NPTS / 256, 256, 0, stream>>>(inp, emb, ws, out, NPTS / 256);
}

// Round 8
// 169.551 us; speedup vs baseline: 8.0324x; 8.0324x over previous
//
#include <hip/hip_runtime.h>
#include <stdint.h>

// VQ-VAE vector quantizer — fp32, NCHW input [64,64,32,32], emb [1024,64].
// Architecture (r7-proven math, re-engineered machinery):
//   sweep1: bf16 MFMA dk for all (point,code) -> per-point dmin (registers)
//   window: thr = dmin + 2*(2^-6*sqrt(A)*emax + 6e-5)  [provable superset of
//           all k whose EXACT np-fp32 ref distance can be the ref min]
//   sweep2: same MFMA; candidates via __ballot + single-owner LDS writes
//           (NO atomics, NO predicated global ops -> no spill pathology)
//   rescue: cnt==1 -> winner; else exact np-fp32 eval (r3-proven bit-exact)
//   epilogue: quantized NCHW + loss + ticket finalize. All in ONE kernel.
constexpr int KCODES = 1024;
constexpr int DDIM   = 64;
constexpr int HW     = 1024;
constexpr int NPTS   = 65536;

constexpr int OUT_Q    = 0;
constexpr int OUT_IDX  = 4194304;
constexpr int OUT_LOSS = 4259840;
constexpr int OUT_NLL  = 4259841;

// ws float-offsets
constexpr size_t WS_C      = 0;        // 1024 f : C_k (np-pairwise, exact)
constexpr size_t WS_LOSS   = 1024;
constexpr size_t WS_TICKET = 1025;
constexpr size_t WS_EMAX   = 1026;
constexpr size_t WS_A      = 2048;               // 65536 f : A_n (exact)
constexpr size_t WS_EB     = WS_A + NPTS;        // 1024*64 bf16 = 32768 f
constexpr size_t WS_XB     = WS_EB + 32768;      // 65536*64 bf16 = 2097152 f

typedef __attribute__((ext_vector_type(8))) short short8v;
typedef __attribute__((ext_vector_type(4))) float float4v;

__device__ __forceinline__ uint16_t f2bf(float f) {   // RNE fp32->bf16
    uint32_t u = __float_as_uint(f);
    return (uint16_t)((u + 0x7fffu + ((u >> 16) & 1u)) >> 16);
}

__device__ __forceinline__ float np_pairwise_sumsq64(const float* a) {
    float r[8];
    #pragma unroll
    for (int j = 0; j < 8; ++j) r[j] = __fmul_rn(a[j], a[j]);
    #pragma unroll
    for (int i = 8; i < 64; i += 8)
        #pragma unroll
        for (int j = 0; j < 8; ++j)
            r[j] = __fadd_rn(r[j], __fmul_rn(a[i + j], a[i + j]));
    return __fadd_rn(__fadd_rn(__fadd_rn(r[0], r[1]), __fadd_rn(r[2], r[3])),
                     __fadd_rn(__fadd_rn(r[4], r[5]), __fadd_rn(r[6], r[7])));
}

// bit-exact ref distance (r3-proven): d = fp32( fp32(A - 2*G_seq) + C_k )
__device__ __forceinline__ float exact_dist(const float* x,
                                            const float* __restrict__ emb,
                                            const float* __restrict__ Cw,
                                            float A, int k) {
    float e[DDIM];
    const float4* e4 = (const float4*)(emb + (size_t)k * DDIM);
    #pragma unroll
    for (int j = 0; j < 16; ++j) ((float4*)e)[j] = e4[j];
    float g = 0.f;
    #pragma unroll
    for (int d = 0; d < DDIM; ++d) g = fmaf(x[d], e[d], g);
    return __fadd_rn(__fsub_rn(A, __fmul_rn(2.0f, g)), Cw[k]);
}

__global__ __launch_bounds__(256) void vq_prep_x(const float* __restrict__ inp,
                                                 float* __restrict__ ws) {
    const int n = blockIdx.x * 256 + threadIdx.x;
    const int b = n >> 10, hw = n & 1023;
    const float* xin = inp + (size_t)b * DDIM * HW + hw;
    float x[DDIM];
    #pragma unroll
    for (int d = 0; d < DDIM; ++d) x[d] = xin[(size_t)d * HW];
    ws[WS_A + n] = np_pairwise_sumsq64(x);
    uint32_t* xb = (uint32_t*)(ws + WS_XB) + (size_t)n * 32;
    #pragma unroll
    for (int j = 0; j < 32; ++j)
        xb[j] = (uint32_t)f2bf(x[2 * j]) | ((uint32_t)f2bf(x[2 * j + 1]) << 16);
}

__global__ __launch_bounds__(1024) void vq_prep_e(const float* __restrict__ emb,
                                                  float* __restrict__ ws) {
    __shared__ float smax[16];
    const int k = threadIdx.x;
    float row[DDIM];
    const float4* src = (const float4*)(emb + (size_t)k * DDIM);
    #pragma unroll
    for (int j = 0; j < 16; ++j) ((float4*)row)[j] = src[j];
    float C = np_pairwise_sumsq64(row);
    ws[WS_C + k] = C;
    uint32_t* ebr = (uint32_t*)(ws + WS_EB) + (size_t)k * 32;
    #pragma unroll
    for (int j = 0; j < 32; ++j)
        ebr[j] = (uint32_t)f2bf(row[2 * j]) | ((uint32_t)f2bf(row[2 * j + 1]) << 16);
    float m = C;
    #pragma unroll
    for (int off = 32; off > 0; off >>= 1) m = fmaxf(m, __shfl_down(m, off, 64));
    if ((k & 63) == 0) smax[k >> 6] = m;
    __syncthreads();
    if (k == 0) {
        float mm = smax[0];
        #pragma unroll
        for (int i = 1; i < 16; ++i) mm = fmaxf(mm, smax[i]);
        ws[WS_EMAX] = sqrtf(mm);
        ws[WS_LOSS] = 0.0f;
        ((unsigned*)ws)[WS_TICKET] = 0u;
    }
}

// Block: 256 thr = 4 waves, 128 points (32/wave). E staged per 256-code chunk
// in LDS, rows padded 128B->144B (breaks the stride-128 bank pathology while
// keeping 16B alignment for ds_read_b128). ~43 KB LDS -> 2 blocks/CU resident.
constexpr int ROWB = 144;   // padded row bytes in LDS

__global__ __launch_bounds__(256, 2) void vq_main(
        const float* __restrict__ inp, const float* __restrict__ emb,
        float* __restrict__ ws, float* __restrict__ out, int nblocks)
{
    __shared__ uint16_t sE[256 * (ROWB / 2)];   // 36864 B
    __shared__ float    sC[256];
    __shared__ uint16_t sCand[128][16];
    __shared__ int      sCnt[128];
    __shared__ int      sWin[128];
    __shared__ float    sred[4];

    const int tid  = threadIdx.x;
    const int lane = tid & 63;
    const int wave = tid >> 6;
    const int col  = lane & 15;
    const int quad = lane >> 4;
    const int base = blockIdx.x * 128 + wave * 32;

    const uint16_t* Xb = (const uint16_t*)(ws + WS_XB);
    const uint16_t* Eb = (const uint16_t*)(ws + WS_EB);

    // A-fragments (r7-verified layout): lane holds X[m=col][k=quad*8+j]
    short8v a[2][2];
    #pragma unroll
    for (int g = 0; g < 2; ++g) {
        const uint16_t* xr = Xb + (size_t)(base + g * 16 + col) * DDIM + quad * 8;
        a[g][0] = *(const short8v*)(xr);
        a[g][1] = *(const short8v*)(xr + 32);
    }
    float Ap[2][4];
    #pragma unroll
    for (int g = 0; g < 2; ++g)
        #pragma unroll
        for (int r = 0; r < 4; ++r)
            Ap[g][r] = ws[WS_A + base + g * 16 + quad * 4 + r];
    const float emax = ws[WS_EMAX];

    // ---------------- sweep 1: dmin ----------------
    float run[2][4];
    #pragma unroll
    for (int g = 0; g < 2; ++g)
        #pragma unroll
        for (int r = 0; r < 4; ++r) run[g][r] = 3.0e38f;

    #pragma unroll 1
    for (int cc = 0; cc < 4; ++cc) {
        const int K0 = cc * 256;
        __syncthreads();
        const uint4* src = (const uint4*)(Eb + (size_t)K0 * DDIM);
        #pragma unroll
        for (int it = 0; it < 8; ++it) {
            int j = it * 256 + tid, row = j >> 3, pos = j & 7;
            *(uint4*)((char*)sE + row * ROWB + pos * 16) = src[j];
        }
        sC[tid] = ws[WS_C + K0 + tid];
        __syncthreads();

        #pragma unroll 2
        for (int c2 = 0; c2 < 16; ++c2) {
            const int kcL = c2 * 16 + col;
            short8v b0 = *(const short8v*)((const char*)sE + kcL * ROWB + quad * 16);
            short8v b1 = *(const short8v*)((const char*)sE + kcL * ROWB + quad * 16 + 64);
            float Ck = sC[kcL];
            #pragma unroll
            for (int g = 0; g < 2; ++g) {
                float4v acc = {0.f, 0.f, 0.f, 0.f};
                acc = __builtin_amdgcn_mfma_f32_16x16x32_bf16(a[g][0], b0, acc, 0, 0, 0);
                acc = __builtin_amdgcn_mfma_f32_16x16x32_bf16(a[g][1], b1, acc, 0, 0, 0);
                #pragma unroll
                for (int r = 0; r < 4; ++r) {
                    float dk = fmaf(-2.0f, acc[r], Ap[g][r]) + Ck;
                    run[g][r] = fminf(run[g][r], dk);
                }
            }
        }
    }

    // reduce over the 16 col-lanes -> thr (all lanes of group get it)
    float thr[2][4];
    #pragma unroll
    for (int g = 0; g < 2; ++g)
        #pragma unroll
        for (int r = 0; r < 4; ++r) {
            float m = run[g][r];
            m = fminf(m, __shfl_xor(m, 1, 16));
            m = fminf(m, __shfl_xor(m, 2, 16));
            m = fminf(m, __shfl_xor(m, 4, 16));
            m = fminf(m, __shfl_xor(m, 8, 16));
            thr[g][r] = m + 2.0f * (0.015625f * sqrtf(Ap[g][r]) * emax + 6e-5f);
        }

    // ---------------- sweep 2: candidates (ballot, owner-lane writes) -------
    int cnt[2][4];
    #pragma unroll
    for (int g = 0; g < 2; ++g)
        #pragma unroll
        for (int r = 0; r < 4; ++r) cnt[g][r] = 0;

    #pragma unroll 1
    for (int cc = 0; cc < 4; ++cc) {
        const int K0 = cc * 256;
        __syncthreads();
        const uint4* src = (const uint4*)(Eb + (size_t)K0 * DDIM);
        #pragma unroll
        for (int it = 0; it < 8; ++it) {
            int j = it * 256 + tid, row = j >> 3, pos = j & 7;
            *(uint4*)((char*)sE + row * ROWB + pos * 16) = src[j];
        }
        sC[tid] = ws[WS_C + K0 + tid];
        __syncthreads();

        #pragma unroll 1
        for (int c2 = 0; c2 < 16; ++c2) {
            const int kcL = c2 * 16 + col;
            short8v b0 = *(const short8v*)((const char*)sE + kcL * ROWB + quad * 16);
            short8v b1 = *(const short8v*)((const char*)sE + kcL * ROWB + quad * 16 + 64);
            float Ck = sC[kcL];
            #pragma unroll
            for (int g = 0; g < 2; ++g) {
                float4v acc = {0.f, 0.f, 0.f, 0.f};
                acc = __builtin_amdgcn_mfma_f32_16x16x32_bf16(a[g][0], b0, acc, 0, 0, 0);
                acc = __builtin_amdgcn_mfma_f32_16x16x32_bf16(a[g][1], b1, acc, 0, 0, 0);
                #pragma unroll
                for (int r = 0; r < 4; ++r) {
                    float dk = fmaf(-2.0f, acc[r], Ap[g][r]) + Ck;
                    unsigned long long m = __ballot(dk <= thr[g][r]);
                    if (col == 0) {               // sole owner of point (g,quad,r)
                        unsigned gm = (unsigned)(m >> (quad * 16)) & 0xffffu;
                        while (gm) {
                            int bit = __ffs(gm) - 1;
                            gm &= gm - 1;
                            int ct = cnt[g][r];
                            if (ct < 16)
                                sCand[wave * 32 + g * 16 + quad * 4 + r][ct] =
                                    (uint16_t)(K0 + c2 * 16 + bit);
                            cnt[g][r] = ct + 1;
                        }
                    }
                }
            }
        }
    }
    if (col == 0) {
        #pragma unroll
        for (int g = 0; g < 2; ++g)
            #pragma unroll
            for (int r = 0; r < 4; ++r)
                sCnt[wave * 32 + g * 16 + quad * 4 + r] = cnt[g][r];
    }
    __syncthreads();

    // ---------------- rescue: exact np-fp32 on candidates --------------------
    if (tid < 128) {
        const int p = tid;
        const int n = blockIdx.x * 128 + p;
        const int c = sCnt[p];
        int win;
        if (c == 1) {
            win = sCand[p][0];       // window superset => sole cand IS ref argmin
        } else {
            const int b = n >> 10, hw = n & 1023;
            const float* xin = inp + (size_t)b * DDIM * HW + hw;
            float x[DDIM];
            #pragma unroll
            for (int d = 0; d < DDIM; ++d) x[d] = xin[(size_t)d * HW];
            const float A = ws[WS_A + n];
            const float* Cw = ws + WS_C;
            float bd = 3.0e38f; win = KCODES;
            if (c <= 16) {
                #pragma unroll 1
                for (int i = 0; i < c; ++i) {
                    int k = sCand[p][i];
                    float dd = exact_dist(x, emb, Cw, A, k);
                    if (dd < bd || (dd == bd && k < win)) { bd = dd; win = k; }
                }
            } else {                 // overflow safety: full exact scan
                #pragma unroll 1
                for (int k = 0; k < KCODES; ++k) {
                    float dd = exact_dist(x, emb, Cw, A, k);
                    if (dd < bd) { bd = dd; win = k; }
                }
            }
        }
        sWin[p] = win;
        out[OUT_IDX + n] = (float)win;
    }
    __syncthreads();

    // ---------------- epilogue: quantized NCHW + loss ------------------------
    {
        const int pl = tid & 127, half = tid >> 7;
        const int n2 = blockIdx.x * 128 + pl;
        const int b2 = n2 >> 10, hw2 = n2 & 1023;
        const int win = sWin[pl];
        float q[32];
        const float4* q4 = (const float4*)(emb + (size_t)win * DDIM + half * 32);
        #pragma unroll
        for (int j = 0; j < 8; ++j) ((float4*)q)[j] = q4[j];
        const float* xin2 = inp + (size_t)b2 * DDIM * HW + hw2 + (size_t)half * 32 * HW;
        float* orow = out + (size_t)b2 * DDIM * HW + hw2 + (size_t)half * 32 * HW;
        float lacc = 0.f;
        #pragma unroll
        for (int j = 0; j < 32; ++j) {
            float xv = xin2[(size_t)j * HW];
            float diff = __fsub_rn(q[j], xv);
            orow[(size_t)j * HW] = __fadd_rn(xv, diff);   // ref's x + (q - x)
            lacc = fmaf(diff, diff, lacc);
        }
        #pragma unroll
        for (int off = 32; off > 0; off >>= 1) lacc += __shfl_down(lacc, off, 64);
        if (lane == 0) sred[wave] = lacc;
    }
    __syncthreads();
    if (tid == 0) {
        atomicAdd(ws + WS_LOSS, sred[0] + sred[1] + sred[2] + sred[3]);
        __threadfence();
        unsigned old = atomicAdd((unsigned*)ws + WS_TICKET, 1u);
        if (old == (unsigned)(nblocks - 1)) {
            __threadfence();
            float L = __hip_atomic_load(ws + WS_LOSS, __ATOMIC_RELAXED,
                                        __HIP_MEMORY_SCOPE_AGENT);
            out[OUT_LOSS] = L * (1.25f / 4194304.0f);
            out[OUT_NLL]  = 1.0f;
        }
    }
}

extern "C" void kernel_launch(void* const* d_in, const int* in_sizes, int n_in,
                              void* d_out, int out_size, void* d_ws, size_t ws_size,
                              hipStream_t stream) {
    const float* inp = (const float*)d_in[0];
    const float* emb = (const float*)d_in[1];
    float* out = (float*)d_out;
    float* ws  = (float*)d_ws;

    vq_prep_x<<<NPTS / 256, 256, 0, stream>>>(inp, ws);
    vq_prep_e<<<1, 1024, 0, stream>>>(emb, ws);
    vq_main<<<NPTS / 128, 256, 0, stream>>>(inp, emb, ws, out, NPTS / 128);
}